// Round 1
// 95.520 us; speedup vs baseline: 1.0447x; 1.0447x over previous
//
#include <hip/hip_runtime.h>
#include <math.h>

// Chamfer loss, two 16384x3 fp32 clouds.
// R5: (a) drop LDS staging entirely -- the DB slice is wave-uniform and
//     L2-resident, so stream it through SGPRs (s_load of a pre-packed
//     {x0,x1,y0,y1}{z0,z1,w0,w1} pair array; pk_fma takes the SGPR pair as
//     src0, 1 sgpr/instr). No loader phase, no __syncthreads, no ds_read
//     lgkm stalls in the inner loop.
//     (b) QPT 16->8, S 128->64: same grid (1024 = 4 blocks/CU) but atomic
//     count halves (4.2M -> 2.1M; WRITE_SIZE was exactly atomics*4B).
//     (c) prep kernel replaces both memsets (packs pairs + inits mins/out):
//     4 graph ops -> 3.

typedef float v2f __attribute__((ext_vector_type(2)));

#define QPT 8   // queries per thread; chunk = 2048 queries

struct Pair { float4 a; float4 b; };   // a={x0,x1,y0,y1} b={z0,z1,w0,w1}

// Monotone float->uint map: a<b  <=>  enc(a)<enc(b).
__device__ __forceinline__ unsigned enc_f32(float f) {
    int b = __float_as_int(f);
    return (b >= 0) ? ((unsigned)b | 0x80000000u) : ~(unsigned)b;
}
__device__ __forceinline__ float dec_f32(unsigned k) {
    int b = (k & 0x80000000u) ? (int)(k & 0x7FFFFFFFu) : ~(int)k;
    return __int_as_float(b);
}

// Pack DB pairs (w = ||p||^2 precomputed), init mins to +inf-enc, out to 0.
// One thread per pair; pair t < N/2 comes from state_x, else from target.
__global__ __launch_bounds__(256) void chamfer_prep(
    const float* __restrict__ state_x, const float* __restrict__ target,
    Pair* __restrict__ pairs, unsigned* __restrict__ mins_u,
    float* __restrict__ out, int N)
{
    const int t = blockIdx.x * 256 + threadIdx.x;      // pair id in [0, N)
    const int half = N >> 1;                           // pairs per cloud
    const float* src = (t < half) ? state_x : target;
    const int j = 2 * ((t < half) ? t : t - half);
    const float x0 = src[3*j+0], y0 = src[3*j+1], z0 = src[3*j+2];
    const float x1 = src[3*j+3], y1 = src[3*j+4], z1 = src[3*j+5];
    Pair p;
    p.a = make_float4(x0, x1, y0, y1);
    p.b = make_float4(z0, z1,
                      fmaf(x0, x0, fmaf(y0, y0, z0 * z0)),
                      fmaf(x1, x1, fmaf(y1, y1, z1 * z1)));
    pairs[t] = p;
    mins_u[2*t+0] = 0xFFFFFFFFu;
    mins_u[2*t+1] = 0xFFFFFFFFu;
    if (t == 0) *out = 0.0f;
}

// Main: per block, 2048 queries (8/thread, in registers) x one 128-pair DB
// slice streamed via uniform (scalar) loads. 3 pk_fma + 1 min3 per (q, 2pts).
__global__ __launch_bounds__(256) void chamfer_main(
    const float* __restrict__ state_x, const float* __restrict__ target,
    const Pair* __restrict__ pairs, unsigned* __restrict__ mins_u,
    int N, int S)
{
    const int tid = threadIdx.x;
    const int qchunk = blockIdx.x / S;          // uniform per block
    const int s = blockIdx.x % S;
    const int qbase = qchunk * (256 * QPT);     // in [0, 2N)
    const int half = N >> 1;

    const float* qcloud;
    const Pair* db;
    int qoff;
    if (qbase < N) { qcloud = target;  db = pairs;        qoff = qbase;     }
    else           { qcloud = state_x; db = pairs + half; qoff = qbase - N; }

    // Per-thread queries: -2*coord; compiler splats via op_sel (VGPR stays scalar).
    v2f mx[QPT], my[QPT], mz[QPT];
    float m[QPT];
    #pragma unroll
    for (int q = 0; q < QPT; ++q) {
        const int qidx = qoff + q * 256 + tid;
        const float x = -2.0f * qcloud[3 * qidx + 0];
        const float y = -2.0f * qcloud[3 * qidx + 1];
        const float z = -2.0f * qcloud[3 * qidx + 2];
        mx[q] = (v2f){x, x};
        my[q] = (v2f){y, y};
        mz[q] = (v2f){z, z};
        m[q] = 3.0e38f;
    }

    const int pps = half / S;                   // 128 pairs per slice
    const Pair* pk = db + s * pps;              // uniform -> s_load stream

    #pragma unroll 4
    for (int p = 0; p < pps; ++p) {
        const float4 A = pk[p].a;               // x0 x1 y0 y1  (wave-uniform)
        const float4 B = pk[p].b;               // z0 z1 w0 w1
        const v2f X = (v2f){A.x, A.y};
        const v2f Y = (v2f){A.z, A.w};
        const v2f Z = (v2f){B.x, B.y};
        const v2f W = (v2f){B.z, B.w};
        #pragma unroll
        for (int q = 0; q < QPT; ++q) {
            v2f d = __builtin_elementwise_fma(X, mx[q], W);
            d = __builtin_elementwise_fma(Y, my[q], d);
            d = __builtin_elementwise_fma(Z, mz[q], d);
            m[q] = fminf(fminf(m[q], d.x), d.y);   // v_min3_f32
        }
    }

    #pragma unroll
    for (int q = 0; q < QPT; ++q) {
        const int qi = qbase + q * 256 + tid;
        atomicMin(&mins_u[qi], enc_f32(m[q]));
    }
}

// Wide finish: decode min, add ||a||^2, sqrt, block-reduce, one atomicAdd.
__global__ __launch_bounds__(256) void chamfer_finish(
    const float* __restrict__ state_x, const float* __restrict__ target,
    const unsigned* __restrict__ mins_u, float* __restrict__ out, int N)
{
    const int tid = threadIdx.x;
    const int qi = blockIdx.x * 256 + tid;

    const float* qcloud = (qi < N) ? target : state_x;
    const int qidx = (qi < N) ? qi : qi - N;
    const float qx = qcloud[3 * qidx + 0];
    const float qy = qcloud[3 * qidx + 1];
    const float qz = qcloud[3 * qidx + 2];
    const float a2 = qx * qx + qy * qy + qz * qz;

    const float mm = dec_f32(mins_u[qi]);
    float v = sqrtf(fmaxf(a2 + mm, 0.0f));

    for (int off = 32; off > 0; off >>= 1) v += __shfl_down(v, off, 64);
    __shared__ float wsum[4];
    if ((tid & 63) == 0) wsum[tid >> 6] = v;
    __syncthreads();
    if (tid == 0) {
        const float bsum = wsum[0] + wsum[1] + wsum[2] + wsum[3];
        atomicAdd(out, bsum * 5.0f / (float)N);  // (mean1+mean2)*0.5*10
    }
}

extern "C" void kernel_launch(void* const* d_in, const int* in_sizes, int n_in,
                              void* d_out, int out_size, void* d_ws, size_t ws_size,
                              hipStream_t stream)
{
    const float* state_x = (const float*)d_in[0];
    const float* target  = (const float*)d_in[1];
    float* out = (float*)d_out;

    const int N = in_sizes[0] / 3;               // 16384
    const int twoN = 2 * N;

    // S slices of each cloud's pair array; (N/2) % S == 0.
    int S = 64;
    while (S > 1 && ((N / 2) % S) != 0) S >>= 1;

    // Workspace: [0, 2N*4) mins_u ; [2N*4, 2N*4 + N*32) packed pairs (640 KB).
    unsigned* mins_u = (unsigned*)d_ws;
    Pair* pairs = (Pair*)((char*)d_ws + (size_t)twoN * sizeof(unsigned));

    const int nQChunks = twoN / (256 * QPT);     // 16

    chamfer_prep<<<N / 256, 256, 0, stream>>>(state_x, target, pairs, mins_u, out, N);
    chamfer_main<<<nQChunks * S, 256, 0, stream>>>(state_x, target, pairs, mins_u, N, S);
    chamfer_finish<<<twoN / 256, 256, 0, stream>>>(state_x, target, mins_u, out, N);
}

// Round 2
// 91.360 us; speedup vs baseline: 1.0923x; 1.0455x over previous
//
#include <hip/hip_runtime.h>
#include <math.h>

// Chamfer loss, two 16384x3 fp32 clouds.
// R6: move distance evals to the matrix pipe. d = |q|^2+|p|^2-2 q.p is packed
//     into ONE v_mfma_f32_32x32x16_bf16 per 32x32 tile via bf16 hi/lo
//     splitting across the 16 K slots:
//       k0-2 : h(-2q).h(p)   k3-5 : l(-2q).h(p)
//       k6-8 : h(-2q).l(p)   k9-11: l(-2q).l(p)
//       k12-13: |q|^2 hi/lo . 1    k14-15: 1 . |p|^2 hi/lo
//     => fp32-accurate d (err ~2^-17) with fp32 MFMA accumulation.
//     Row-mins accumulate in regs (16 f32/lane, v_min3 folds 2 tiles/pass);
//     one butterfly + 32 atomicMin per wave (262K atomics, was 2.1M).
//     VALU work per eval drops ~40x; MfmaUtil was 0.

typedef __attribute__((ext_vector_type(8)))  short bf16x8;   // 8 bf16 = 4 VGPR
typedef __attribute__((ext_vector_type(16))) float f32x16;   // MFMA C/D

#define S_SLICES 8   // col slices per direction; grid = (2N/128)*S

// Monotone float->uint map: a<b  <=>  enc(a)<enc(b).
__device__ __forceinline__ unsigned enc_f32(float f) {
    int b = __float_as_int(f);
    return (b >= 0) ? ((unsigned)b | 0x80000000u) : ~(unsigned)b;
}
__device__ __forceinline__ float dec_f32(unsigned k) {
    int b = (k & 0x80000000u) ? (int)(k & 0x7FFFFFFFu) : ~(int)k;
    return __int_as_float(b);
}

// fp32 -> bf16 (RNE), and back.
__device__ __forceinline__ unsigned short f2bf(float v) {
    unsigned u = __float_as_uint(v);
    u += 0x7FFFu + ((u >> 16) & 1u);
    return (unsigned short)(u >> 16);
}
__device__ __forceinline__ float bf2f(unsigned short b) {
    unsigned u = ((unsigned)b) << 16;
    return __uint_as_float(u);
}
__device__ __forceinline__ unsigned pk2(unsigned short lo, unsigned short hi) {
    return (unsigned)lo | ((unsigned)hi << 16);
}

// Build A-role and B-role K=16 fragments for every point of both clouds.
// Also init mins_u and out. One thread per point (2N threads).
__global__ __launch_bounds__(256) void chamfer_prep(
    const float* __restrict__ state_x, const float* __restrict__ target,
    uint4* __restrict__ AfragS, uint4* __restrict__ AfragT,
    uint4* __restrict__ BfragS, uint4* __restrict__ BfragT,
    unsigned* __restrict__ mins_u, float* __restrict__ out, int N)
{
    const int p = blockIdx.x * 256 + threadIdx.x;     // [0, 2N)
    const float* src = (p < N) ? state_x : target;
    const int i = (p < N) ? p : p - N;

    const float x = src[3*i+0], y = src[3*i+1], z = src[3*i+2];
    const float n2 = fmaf(x, x, fmaf(y, y, z * z));

    // hi/lo splits (RNE both stages; residual ~2^-18 rel).
    const unsigned short hx = f2bf(x), hy = f2bf(y), hz = f2bf(z);
    const unsigned short lx = f2bf(x - bf2f(hx));
    const unsigned short ly = f2bf(y - bf2f(hy));
    const unsigned short lz = f2bf(z - bf2f(hz));
    // -2*coord splits (exact -2 scaling of the same split).
    const unsigned short mhx = f2bf(-2.0f*x), mhy = f2bf(-2.0f*y), mhz = f2bf(-2.0f*z);
    const unsigned short mlx = f2bf(-2.0f*x - bf2f(mhx));
    const unsigned short mly = f2bf(-2.0f*y - bf2f(mhy));
    const unsigned short mlz = f2bf(-2.0f*z - bf2f(mhz));
    const unsigned short hn = f2bf(n2);
    const unsigned short ln = f2bf(n2 - bf2f(hn));
    const unsigned short ONE = 0x3F80;

    // A-role: [mh(3), ml(3), mh(3), ml(3), hn, ln, 1, 1]
    uint4 A0 = make_uint4(pk2(mhx,mhy), pk2(mhz,mlx), pk2(mly,mlz), pk2(mhx,mhy));
    uint4 A1 = make_uint4(pk2(mhz,mlx), pk2(mly,mlz), pk2(hn,ln),   pk2(ONE,ONE));
    // B-role: [h(3), h(3), l(3), l(3), 1, 1, hn, ln]
    uint4 B0 = make_uint4(pk2(hx,hy), pk2(hz,hx), pk2(hy,hz), pk2(lx,ly));
    uint4 B1 = make_uint4(pk2(lz,lx), pk2(ly,lz), pk2(ONE,ONE), pk2(hn,ln));

    uint4* Aarr = (p < N) ? AfragS : AfragT;
    uint4* Barr = (p < N) ? BfragS : BfragT;
    Aarr[2*i+0] = A0;  Aarr[2*i+1] = A1;
    Barr[2*i+0] = B0;  Barr[2*i+1] = B1;

    mins_u[p] = 0xFFFFFFFFu;
    if (p == 0) *out = 0.0f;
}

// Main: wave = 32 query rows x C cols (C/32 tiles, 2 tiles folded per min3
// pass). One 32x32x16 bf16 MFMA per tile computes complete d values.
__global__ __launch_bounds__(256) void chamfer_main(
    const bf16x8* __restrict__ AfragS, const bf16x8* __restrict__ AfragT,
    const bf16x8* __restrict__ BfragS, const bf16x8* __restrict__ BfragT,
    unsigned* __restrict__ mins_u, int N, int S)
{
    const int tid  = threadIdx.x;
    const int lane = tid & 63;
    const int l31  = lane & 31;
    const int half = lane >> 5;
    const int w    = tid >> 6;

    const int bs = blockIdx.x / S;            // row-block (128 rows)
    const int s  = blockIdx.x % S;            // col slice
    const int qrow0 = bs * 128 + w * 32;      // [0, 2N)

    const bf16x8* afr;
    const bf16x8* bfr;
    if (qrow0 < N) { afr = AfragT + (size_t)qrow0 * 2;       bfr = BfragS; }
    else           { afr = AfragS + (size_t)(qrow0 - N) * 2; bfr = BfragT; }

    // A fragment: row = l31, k-half = half. Loaded once per wave.
    const bf16x8 av = afr[l31 * 2 + half];

    const int C = N / S;                      // cols per slice (2048)
    const bf16x8* bp = bfr + (size_t)(s * C) * 2;
    const int boff = l31 * 2 + half;

    f32x16 racc;
    #pragma unroll
    for (int i = 0; i < 16; ++i) racc[i] = 3.0e38f;
    f32x16 zc;
    #pragma unroll
    for (int i = 0; i < 16; ++i) zc[i] = 0.0f;

    #pragma unroll 2
    for (int it = 0; it < C / 64; ++it) {
        const bf16x8 b0 = bp[it * 128 + boff];        // cols it*64    + l31
        const bf16x8 b1 = bp[it * 128 + 64 + boff];   // cols it*64+32 + l31
        f32x16 acc0 = __builtin_amdgcn_mfma_f32_32x32x16_bf16(av, b0, zc, 0, 0, 0);
        f32x16 acc1 = __builtin_amdgcn_mfma_f32_32x32x16_bf16(av, b1, zc, 0, 0, 0);
        #pragma unroll
        for (int i = 0; i < 16; ++i)
            racc[i] = fminf(fminf(racc[i], acc0[i]), acc1[i]);   // v_min3
    }

    // Row-min across the 32 cols (lanes of each half). Halves hold disjoint
    // rows, so only a 5-stage butterfly within the 32-lane group is needed.
    #pragma unroll
    for (int i = 0; i < 16; ++i) {
        float v = racc[i];
        v = fminf(v, __shfl_xor(v, 16, 64));
        v = fminf(v, __shfl_xor(v,  8, 64));
        v = fminf(v, __shfl_xor(v,  4, 64));
        v = fminf(v, __shfl_xor(v,  2, 64));
        v = fminf(v, __shfl_xor(v,  1, 64));
        racc[i] = v;
    }

    if (l31 == 0) {
        #pragma unroll
        for (int i = 0; i < 16; ++i) {
            const int row = (i & 3) + 8 * (i >> 2) + 4 * half;  // m74/m101 C/D map
            atomicMin(&mins_u[qrow0 + row], enc_f32(racc[i]));
        }
    }
}

// Finish: mins now hold complete d. sqrt, block-reduce, one atomicAdd.
__global__ __launch_bounds__(256) void chamfer_finish(
    const unsigned* __restrict__ mins_u, float* __restrict__ out, int N)
{
    const int tid = threadIdx.x;
    const int qi = blockIdx.x * 256 + tid;

    float v = sqrtf(fmaxf(dec_f32(mins_u[qi]), 0.0f));

    for (int off = 32; off > 0; off >>= 1) v += __shfl_down(v, off, 64);
    __shared__ float wsum[4];
    if ((tid & 63) == 0) wsum[tid >> 6] = v;
    __syncthreads();
    if (tid == 0) {
        const float bsum = wsum[0] + wsum[1] + wsum[2] + wsum[3];
        atomicAdd(out, bsum * 5.0f / (float)N);  // (mean1+mean2)*0.5*10
    }
}

extern "C" void kernel_launch(void* const* d_in, const int* in_sizes, int n_in,
                              void* d_out, int out_size, void* d_ws, size_t ws_size,
                              hipStream_t stream)
{
    const float* state_x = (const float*)d_in[0];
    const float* target  = (const float*)d_in[1];
    float* out = (float*)d_out;

    const int N = in_sizes[0] / 3;               // 16384
    const int twoN = 2 * N;

    int S = S_SLICES;
    while (S > 1 && (N % (S * 64)) != 0) S >>= 1;

    // Workspace layout: mins (2N u32, 128KB) | AfragS | AfragT | BfragS | BfragT
    // (each frag array N*32B = 512KB; total ~2.25MB).
    char* wsb = (char*)d_ws;
    unsigned* mins_u = (unsigned*)wsb;
    uint4* AfragS = (uint4*)(wsb + (size_t)twoN * 4);
    uint4* AfragT = (uint4*)(wsb + (size_t)twoN * 4 + (size_t)N * 32);
    uint4* BfragS = (uint4*)(wsb + (size_t)twoN * 4 + (size_t)N * 64);
    uint4* BfragT = (uint4*)(wsb + (size_t)twoN * 4 + (size_t)N * 96);

    chamfer_prep<<<twoN / 256, 256, 0, stream>>>(
        state_x, target, AfragS, AfragT, BfragS, BfragT, mins_u, out, N);

    const int rowBlocks = twoN / 128;            // 256
    chamfer_main<<<rowBlocks * S, 256, 0, stream>>>(
        (const bf16x8*)AfragS, (const bf16x8*)AfragT,
        (const bf16x8*)BfragS, (const bf16x8*)BfragT, mins_u, N, S);

    chamfer_finish<<<twoN / 256, 256, 0, stream>>>(mins_u, out, N);
}